// Round 7
// baseline (531.168 us; speedup 1.0000x reference)
//
#include <hip/hip_runtime.h>
#include <math.h>

#define NN 30000
#define NE 480000
#define NBLK 118   // ceil(30000/256)
#define NMT 235    // ceil(30000/128) MFMA row-tiles
#define NTRB 7500  // blocks in tr pass (64 edges/block)
#define CAPD 128   // LDS-cached attention weights per node

typedef unsigned short ushort_t;
typedef unsigned int uint_t;
typedef __attribute__((ext_vector_type(8))) short short8;
typedef __attribute__((ext_vector_type(4))) float f32x4;

__device__ __forceinline__ ushort_t f2bf(float x) {
  uint_t u = __float_as_uint(x);
  u = (u + 0x7FFF + ((u >> 16) & 1)) >> 16;
  return (ushort_t)u;
}
__device__ __forceinline__ float bf2f(ushort_t v) {
  return __uint_as_float(((uint_t)v) << 16);
}

__device__ __forceinline__ float wred(float v) {
#pragma unroll
  for (int off = 32; off > 0; off >>= 1) v += __shfl_xor(v, off);
  return v;
}

// ---------------- prep: zero head + 5 weight transposes + feat0/feat1 -> bf16 ----------------
__global__ void prep_kernel(float4* __restrict__ zp, const float* __restrict__ W0,
                            const float* __restrict__ W1, const float* __restrict__ W2,
                            const float* __restrict__ W3, const float* __restrict__ W4,
                            ushort_t* __restrict__ T0, ushort_t* __restrict__ T1,
                            ushort_t* __restrict__ T2, ushort_t* __restrict__ T3,
                            ushort_t* __restrict__ T4, const float* __restrict__ F0,
                            const float* __restrict__ F1, ushort_t* __restrict__ B0,
                            ushort_t* __restrict__ B1) {
  int id = blockIdx.x * 256 + threadIdx.x;
  if (id < 52501) {
    zp[id] = make_float4(0.f, 0.f, 0.f, 0.f);
    return;
  }
  int wid = id - 52501;
  if (wid < 147456) {
    const float* W;
    ushort_t* T;
    int K, N, base;
    if (wid < 65536) { W = W0; T = T0; K = 256; N = 256; base = 0; }
    else if (wid < 98304) { W = W1; T = T1; K = 128; N = 256; base = 65536; }
    else if (wid < 114688) { W = W2; T = T2; K = 256; N = 64; base = 98304; }
    else if (wid < 131072) { W = W3; T = T3; K = 256; N = 64; base = 114688; }
    else { W = W4; T = T4; K = 256; N = 64; base = 131072; }
    int l = wid - base;
    int k = l / N, n = l - k * N;
    T[(size_t)n * K + k] = f2bf(W[l]);
    return;
  }
  int cid = wid - 147456;
  const float* S;
  ushort_t* D;
  if (cid < 960000) { S = F0; D = B0; }
  else {
    cid -= 960000;
    if (cid >= 480000) return;
    S = F1; D = B1;
  }
  const float4* p = (const float4*)(S + (size_t)cid * 8);
  float4 a = p[0], b = p[1];
  short8 o;
  o[0] = (short)f2bf(a.x); o[1] = (short)f2bf(a.y);
  o[2] = (short)f2bf(a.z); o[3] = (short)f2bf(a.w);
  o[4] = (short)f2bf(b.x); o[5] = (short)f2bf(b.y);
  o[6] = (short)f2bf(b.z); o[7] = (short)f2bf(b.w);
  *(short8*)(D + (size_t)cid * 8) = o;
}

// ================= MFMA cores =================

// BN=64 core, fp32 A via LDS (sen path only)
__device__ __forceinline__ void mfma_core_f32(const float* __restrict__ A0,
                                              const ushort_t* __restrict__ BT, int K, int bm,
                                              short* __restrict__ As, short* __restrict__ Bs,
                                              f32x4 acc[2][4]) {
  int tid = threadIdx.x;
  int lane = tid & 63, w = tid >> 6;
  int q = lane >> 4, mr = lane & 15;
#pragma unroll 1
  for (int k0 = 0; k0 < K; k0 += 32) {
    {
      int r = tid >> 1, hf = tid & 1;
      int gr = bm + r;
      float4 f0 = make_float4(0.f, 0.f, 0.f, 0.f), f1 = f0, f2 = f0, f3 = f0;
      if (gr < NN) {
        const float4* pa = (const float4*)(A0 + (size_t)gr * K + k0 + hf * 16);
        f0 = pa[0]; f1 = pa[1]; f2 = pa[2]; f3 = pa[3];
      }
      short8 lo, hi;
      lo[0] = (short)f2bf(f0.x); lo[1] = (short)f2bf(f0.y);
      lo[2] = (short)f2bf(f0.z); lo[3] = (short)f2bf(f0.w);
      lo[4] = (short)f2bf(f1.x); lo[5] = (short)f2bf(f1.y);
      lo[6] = (short)f2bf(f1.z); lo[7] = (short)f2bf(f1.w);
      hi[0] = (short)f2bf(f2.x); hi[1] = (short)f2bf(f2.y);
      hi[2] = (short)f2bf(f2.z); hi[3] = (short)f2bf(f2.w);
      hi[4] = (short)f2bf(f3.x); hi[5] = (short)f2bf(f3.y);
      hi[6] = (short)f2bf(f3.z); hi[7] = (short)f2bf(f3.w);
      short* dst = As + r * 40 + hf * 16;
      *(short8*)(dst) = lo;
      *(short8*)(dst + 8) = hi;
    }
    {
      int n = tid >> 2, qk = tid & 3;
      short8 bv = *(const short8*)((const short*)BT + (size_t)n * K + k0 + qk * 8);
      *(short8*)(Bs + n * 40 + qk * 8) = bv;
    }
    __syncthreads();
    short8 a0 = *(short8*)(As + (w * 32 + mr) * 40 + q * 8);
    short8 a1 = *(short8*)(As + (w * 32 + 16 + mr) * 40 + q * 8);
#pragma unroll
    for (int j = 0; j < 4; ++j) {
      short8 b = *(short8*)(Bs + (j * 16 + mr) * 40 + q * 8);
      acc[0][j] = __builtin_amdgcn_mfma_f32_16x16x32_bf16(a0, b, acc[0][j], 0, 0, 0);
      acc[1][j] = __builtin_amdgcn_mfma_f32_16x16x32_bf16(a1, b, acc[1][j], 0, 0, 0);
    }
    __syncthreads();
  }
}

// BN=128 LDS-FREE core, bf16 A. Fragment loads straight from global:
// wave reads 16 rows x 64B per k-step (coalesced 64B segments); B is L2-resident.
template <int K>
__device__ __forceinline__ void mfma_core2_direct(const ushort_t* __restrict__ A0,
                                                  const ushort_t* __restrict__ BT, int bm,
                                                  f32x4 acc[2][8]) {
  int lane = threadIdx.x & 63, w = threadIdx.x >> 6;
  int q = lane >> 4, mr = lane & 15;
  int gr0 = bm + w * 32 + mr;
  int gr1 = gr0 + 16;
  if (gr0 >= NN) gr0 = NN - 1;  // clamp: rows >= NN never written in epilogue
  if (gr1 >= NN) gr1 = NN - 1;
  const short* pa0 = (const short*)A0 + (size_t)gr0 * K + q * 8;
  const short* pa1 = (const short*)A0 + (size_t)gr1 * K + q * 8;
  const short* pb = (const short*)BT + (size_t)mr * K + q * 8;
#pragma unroll 2
  for (int k0 = 0; k0 < K; k0 += 32) {
    short8 a0 = *(const short8*)(pa0 + k0);
    short8 a1 = *(const short8*)(pa1 + k0);
    short8 b[8];
#pragma unroll
    for (int j = 0; j < 8; ++j) b[j] = *(const short8*)(pb + (size_t)j * 16 * K + k0);
#pragma unroll
    for (int j = 0; j < 8; ++j) {
      acc[0][j] = __builtin_amdgcn_mfma_f32_16x16x32_bf16(a0, b[j], acc[0][j], 0, 0, 0);
      acc[1][j] = __builtin_amdgcn_mfma_f32_16x16x32_bf16(a1, b[j], acc[1][j], 0, 0, 0);
    }
  }
}

// ---- merged GEMM phase: grid (NMT, 5)
// y=0,1: h0 head-pairs (bf16 direct); y=2,3: h1 head-pairs (bf16 direct); y=4: gcn1 (fp32 LDS)
__global__ __launch_bounds__(256) void mfma_all_kernel(
    const ushort_t* __restrict__ fB0, const ushort_t* __restrict__ fB1,
    const float* __restrict__ sen, const ushort_t* __restrict__ WT0,
    const ushort_t* __restrict__ WT1, const ushort_t* __restrict__ Wg1T,
    ushort_t* __restrict__ h0, ushort_t* __restrict__ h1, ushort_t* __restrict__ gcnA,
    const float* __restrict__ al0, const float* __restrict__ ar0, float* __restrict__ el0,
    float* __restrict__ er0, const float* __restrict__ al1, const float* __restrict__ ar1,
    float* __restrict__ el1, float* __restrict__ er1, const float* __restrict__ rdo) {
  __shared__ short As[128 * 40];
  __shared__ short Bs[128 * 40];
  int y = blockIdx.y;
  int bm = blockIdx.x * 128;
  int lane = threadIdx.x & 63, w = threadIdx.x >> 6;
  int q = lane >> 4, mr = lane & 15;
  if (y < 4) {
    int gsel = y >> 1, p = y & 1;
    const float* al = gsel ? al1 : al0;
    const float* ar = gsel ? ar1 : ar0;
    float* el = gsel ? el1 : el0;
    float* er = gsel ? er1 : er0;
    ushort_t* H = gsel ? h1 : h0;
    f32x4 acc[2][8];
#pragma unroll
    for (int i = 0; i < 2; ++i)
#pragma unroll
      for (int j = 0; j < 8; ++j) acc[i][j] = (f32x4){0.f, 0.f, 0.f, 0.f};
    if (gsel == 0)
      mfma_core2_direct<256>(fB0, WT0 + (size_t)p * 128 * 256, bm, acc);
    else
      mfma_core2_direct<128>(fB1, WT1 + (size_t)p * 128 * 128, bm, acc);
    float alv[8], arv[8];
#pragma unroll
    for (int j = 0; j < 8; ++j) {
      alv[j] = al[p * 128 + j * 16 + mr];
      arv[j] = ar[p * 128 + j * 16 + mr];
    }
#pragma unroll
    for (int i = 0; i < 2; ++i)
#pragma unroll
      for (int r = 0; r < 4; ++r) {
        int gr = bm + w * 32 + i * 16 + q * 4 + r;
        float pl0 = 0.f, pr0 = 0.f, pl1 = 0.f, pr1 = 0.f;
#pragma unroll
        for (int j = 0; j < 4; ++j) {
          pl0 = fmaf(acc[i][j][r], alv[j], pl0);
          pr0 = fmaf(acc[i][j][r], arv[j], pr0);
          pl1 = fmaf(acc[i][j + 4][r], alv[j + 4], pl1);
          pr1 = fmaf(acc[i][j + 4][r], arv[j + 4], pr1);
        }
#pragma unroll
        for (int m = 1; m < 16; m <<= 1) {
          pl0 += __shfl_xor(pl0, m);
          pr0 += __shfl_xor(pr0, m);
          pl1 += __shfl_xor(pl1, m);
          pr1 += __shfl_xor(pr1, m);
        }
        if (gr < NN) {
          if (mr == 0) {
            el[gr * 4 + 2 * p] = pl0;
            er[gr * 4 + 2 * p] = pr0;
            el[gr * 4 + 2 * p + 1] = pl1;
            er[gr * 4 + 2 * p + 1] = pr1;
          }
#pragma unroll
          for (int j = 0; j < 8; ++j)
            H[(size_t)gr * 256 + p * 128 + j * 16 + mr] = f2bf(acc[i][j][r]);
        }
      }
  } else {
    f32x4 acc[2][4];
#pragma unroll
    for (int i = 0; i < 2; ++i)
#pragma unroll
      for (int j = 0; j < 4; ++j) acc[i][j] = (f32x4){0.f, 0.f, 0.f, 0.f};
    mfma_core_f32(sen, Wg1T, 256, bm, As, Bs, acc);
#pragma unroll
    for (int i = 0; i < 2; ++i)
#pragma unroll
      for (int r = 0; r < 4; ++r) {
        int gr = bm + w * 32 + i * 16 + q * 4 + r;
        if (gr < NN) {
          float sc = rdo[gr];
#pragma unroll
          for (int j = 0; j < 4; ++j)
            gcnA[(size_t)gr * 64 + j * 16 + mr] = f2bf(acc[i][j][r] * sc);
        }
      }
  }
}

// ---- attn + Wf projection merged (LDS-free core) ----
__global__ __launch_bounds__(256) void mfma_attnwf_kernel(
    const ushort_t* __restrict__ z0, const ushort_t* __restrict__ z1,
    const ushort_t* __restrict__ WpfT, const float* __restrict__ bp1,
    const float* __restrict__ wp2, float* __restrict__ pbuf, ushort_t* __restrict__ Y0,
    ushort_t* __restrict__ Y1) {
  __shared__ float wsum[4];
  const ushort_t* A = blockIdx.y ? z1 : z0;
  ushort_t* Y = blockIdx.y ? Y1 : Y0;
  int bm = blockIdx.x * 128;
  f32x4 acc[2][8];
#pragma unroll
  for (int i = 0; i < 2; ++i)
#pragma unroll
    for (int j = 0; j < 8; ++j) acc[i][j] = (f32x4){0.f, 0.f, 0.f, 0.f};
  mfma_core2_direct<256>(A, WpfT, bm, acc);
  int lane = threadIdx.x & 63, w = threadIdx.x >> 6;
  int q = lane >> 4, mr = lane & 15;
  float local = 0.f;
#pragma unroll
  for (int j = 0; j < 4; ++j) {
    int col = j * 16 + mr;
    float bp = bp1[col], wp = wp2[col];
#pragma unroll
    for (int i = 0; i < 2; ++i)
#pragma unroll
      for (int r = 0; r < 4; ++r) {
        int gr = bm + w * 32 + i * 16 + q * 4 + r;
        if (gr < NN) local += tanhf(acc[i][j][r] + bp) * wp;
      }
  }
  local = wred(local);
  if (lane == 0) wsum[w] = local;
#pragma unroll
  for (int j = 4; j < 8; ++j) {
    int col = (j - 4) * 16 + mr;
#pragma unroll
    for (int i = 0; i < 2; ++i)
#pragma unroll
      for (int r = 0; r < 4; ++r) {
        int gr = bm + w * 32 + i * 16 + q * 4 + r;
        if (gr < NN) Y[(size_t)gr * 64 + col] = f2bf(acc[i][j][r]);
      }
  }
  __syncthreads();
  if (threadIdx.x == 0)
    pbuf[blockIdx.y * NMT + blockIdx.x] = wsum[0] + wsum[1] + wsum[2] + wsum[3];
}

// ---------------- CSR build ----------------
__global__ void hist_kernel(const int* __restrict__ d0, const int* __restrict__ d1,
                            const int* __restrict__ d2, const int* __restrict__ d3,
                            int* __restrict__ cnt) {
  int g = blockIdx.y;
  const int* d = g == 0 ? d0 : g == 1 ? d1 : g == 2 ? d2 : d3;
  int e = blockIdx.x * 256 + threadIdx.x;
  if (e < NE) atomicAdd(&cnt[g * NN + d[e]], 1);
}

__global__ __launch_bounds__(256) void scan_blocks_kernel(const int* __restrict__ cnt,
                                                          int* __restrict__ rows,
                                                          int* __restrict__ bsum) {
  __shared__ int sm[256];
  int g = blockIdx.y, t = threadIdx.x;
  int i = blockIdx.x * 256 + t;
  int v = (i < NN) ? cnt[g * NN + i] : 0;
  sm[t] = v;
  __syncthreads();
#pragma unroll
  for (int off = 1; off < 256; off <<= 1) {
    int tmp = (t >= off) ? sm[t - off] : 0;
    __syncthreads();
    sm[t] += tmp;
    __syncthreads();
  }
  if (i < NN) rows[g * (NN + 1) + i] = sm[t] - v;  // exclusive
  if (t == 255) bsum[g * NBLK + blockIdx.x] = sm[255];
}

__global__ __launch_bounds__(128) void scan_tops_kernel(int* __restrict__ bsum,
                                                        int* __restrict__ boff) {
  __shared__ int sm[128];
  int g = blockIdx.y, t = threadIdx.x;
  int v = (t < NBLK) ? bsum[g * NBLK + t] : 0;
  sm[t] = v;
  __syncthreads();
#pragma unroll
  for (int off = 1; off < 128; off <<= 1) {
    int tmp = (t >= off) ? sm[t - off] : 0;
    __syncthreads();
    sm[t] += tmp;
    __syncthreads();
  }
  if (t < NBLK) boff[g * NBLK + t] = sm[t] - v;  // exclusive
}

__global__ void add_off_kernel(int* __restrict__ rows, const int* __restrict__ boff) {
  int g = blockIdx.y, t = threadIdx.x;
  int i = blockIdx.x * 256 + t;
  if (i < NN) rows[g * (NN + 1) + i] += boff[g * NBLK + blockIdx.x];
  if (blockIdx.x == 0 && t == 0) rows[g * (NN + 1) + NN] = NE;
}

// scatter (y=0..2) + rdeg (y=3)
__global__ void scatter_kernel(const int* __restrict__ s0, const int* __restrict__ s1,
                               const int* __restrict__ s2, const int* __restrict__ d0,
                               const int* __restrict__ d1, const int* __restrict__ d2,
                               const int* __restrict__ rows, int* __restrict__ cnt2,
                               int* __restrict__ cols, const int* __restrict__ cnt_deg,
                               float* __restrict__ rdo, float* __restrict__ rdi,
                               const int* __restrict__ rows_g) {
  int g = blockIdx.y;
  if (g == 3) {
    int n = blockIdx.x * 256 + threadIdx.x;
    if (n < NN) {
      rdo[n] = rsqrtf(fmaxf((float)cnt_deg[n], 1.f));
      float di = (float)(rows_g[n + 1] - rows_g[n]);
      rdi[n] = rsqrtf(fmaxf(di, 1.f));
    }
    return;
  }
  const int* sp = g == 0 ? s0 : g == 1 ? s1 : s2;
  const int* dp = g == 0 ? d0 : g == 1 ? d1 : d2;
  int e = blockIdx.x * 256 + threadIdx.x;
  if (e >= NE) return;
  int d = dp[e];
  int pos = rows[g * (NN + 1) + d] + atomicAdd(&cnt2[g * NN + d], 1);
  cols[(size_t)g * NE + pos] = sp[e];
}

// ---------------- GAT per-node gather: two-pass, aw in LDS, clamped 16-deep windows --------
__global__ __launch_bounds__(256) void gat_node_kernel(
    const int* __restrict__ rows0, const int* __restrict__ cols0, const float* __restrict__ el0,
    const float* __restrict__ er0, const ushort_t* __restrict__ h0,
    const float* __restrict__ bias0, ushort_t* __restrict__ zz0, const int* __restrict__ rows1,
    const int* __restrict__ cols1, const float* __restrict__ el1, const float* __restrict__ er1,
    const ushort_t* __restrict__ h1, const float* __restrict__ bias1,
    ushort_t* __restrict__ zz1) {
  __shared__ float aw[4][CAPD][4];  // 8 KB
  int g = blockIdx.y;
  const int* rows = g ? rows1 : rows0;
  const int* cols = g ? cols1 : cols0;
  const float* el = g ? el1 : el0;
  const float* er = g ? er1 : er0;
  const ushort_t* h = g ? h1 : h0;
  const float* bias = g ? bias1 : bias0;
  ushort_t* z = g ? zz1 : zz0;

  int lane = threadIdx.x & 63, w = threadIdx.x >> 6;
  int n = blockIdx.x * 4 + w;
  int r0 = rows[n], r1 = rows[n + 1];
  int deg = r1 - r0;
  float4 er4 = *(const float4*)&er[n * 4];
  float s0 = 0.f, s1 = 0.f, s2 = 0.f, s3 = 0.f;
  for (int j = lane; j < deg; j += 64) {
    int s = cols[r0 + j];
    float4 elv = *(const float4*)&el[s * 4];
    float v0 = elv.x + er4.x; v0 = v0 > 0.f ? v0 : 0.2f * v0;
    float v1 = elv.y + er4.y; v1 = v1 > 0.f ? v1 : 0.2f * v1;
    float v2 = elv.z + er4.z; v2 = v2 > 0.f ? v2 : 0.2f * v2;
    float v3 = elv.w + er4.w; v3 = v3 > 0.f ? v3 : 0.2f * v3;
    float e0 = __expf(v0), e1 = __expf(v1), e2 = __expf(v2), e3 = __expf(v3);
    s0 += e0; s1 += e1; s2 += e2; s3 += e3;
    if (j < CAPD) {
      aw[w][j][0] = e0; aw[w][j][1] = e1; aw[w][j][2] = e2; aw[w][j][3] = e3;
    }
  }
  s0 = wred(s0); s1 = wred(s1); s2 = wred(s2); s3 = wred(s3);
  __syncthreads();
  int hh = lane >> 4;
  float denom = hh == 0 ? s0 : hh == 1 ? s1 : hh == 2 ? s2 : s3;
  float myer = hh == 0 ? er4.x : hh == 1 ? er4.y : hh == 2 ? er4.z : er4.w;
  float invd = (deg > 0) ? 1.f / denom : 0.f;
  float4 acc = make_float4(0.f, 0.f, 0.f, 0.f);
  int jc = deg < CAPD ? deg : CAPD;
  // clamped 16-deep windows: 16 outstanding 512B row loads per wave, every iter
  for (int j = 0; j < jc; j += 16) {
    int si[16];
    float ai[16];
#pragma unroll
    for (int t = 0; t < 16; ++t) {
      int jj = j + t;
      int jx = jj < jc ? jj : jc - 1;
      si[t] = cols[r0 + jx];
      ai[t] = (jj < jc) ? aw[w][jj][hh] : 0.f;
    }
    ushort4 ui[16];
#pragma unroll
    for (int t = 0; t < 16; ++t) ui[t] = *(const ushort4*)&h[(size_t)si[t] * 256 + lane * 4];
#pragma unroll
    for (int t = 0; t < 16; ++t) {
      acc.x = fmaf(ai[t], bf2f(ui[t].x), acc.x);
      acc.y = fmaf(ai[t], bf2f(ui[t].y), acc.y);
      acc.z = fmaf(ai[t], bf2f(ui[t].z), acc.z);
      acc.w = fmaf(ai[t], bf2f(ui[t].w), acc.w);
    }
  }
  for (int j = jc; j < deg; ++j) {  // rare overflow beyond CAPD
    int s = cols[r0 + j];
    float v = el[s * 4 + hh] + myer;
    v = v > 0.f ? v : 0.2f * v;
    float a = __expf(v);
    ushort4 hu = *(const ushort4*)&h[(size_t)s * 256 + lane * 4];
    acc.x = fmaf(a, bf2f(hu.x), acc.x);
    acc.y = fmaf(a, bf2f(hu.y), acc.y);
    acc.z = fmaf(a, bf2f(hu.z), acc.z);
    acc.w = fmaf(a, bf2f(hu.w), acc.w);
  }
  float4 bv = *(const float4*)&bias[lane * 4];
  ushort4 o;
  o.x = f2bf(fminf(fmaxf(acc.x * invd + bv.x, 0.f), 6.f));
  o.y = f2bf(fminf(fmaxf(acc.y * invd + bv.y, 0.f), 6.f));
  o.z = f2bf(fminf(fmaxf(acc.z * invd + bv.z, 0.f), 6.f));
  o.w = f2bf(fminf(fmaxf(acc.w * invd + bv.w, 0.f), 6.f));
  *(ushort4*)&z[(size_t)n * 256 + lane * 4] = o;
}

// ---------------- GCN gather1 + gemm64 fused; clamped 16-edge windows; block 0 beta ----------
__global__ __launch_bounds__(256) void gcn_gather12_kernel(
    const int* __restrict__ rows, const int* __restrict__ cols, const ushort_t* __restrict__ X,
    const float* __restrict__ rdi, const float* __restrict__ bg1, const float* __restrict__ Wg2,
    const float* __restrict__ rdo, ushort_t* __restrict__ out2, const float* __restrict__ pbuf,
    float* __restrict__ wb) {
  __shared__ float psm[4][64];
  int lane = threadIdx.x & 63, w = threadIdx.x >> 6;
  // ---- folded attn_reduce (block 0 only) ----
  if (blockIdx.x == 0) {
    __shared__ float sm[8];
    int t = threadIdx.x;
    float a0 = 0.f, a1 = 0.f;
    for (int i = t; i < NMT; i += 256) {
      a0 += pbuf[i];
      a1 += pbuf[NMT + i];
    }
    a0 = wred(a0);
    a1 = wred(a1);
    if (lane == 0) { sm[w] = a0; sm[4 + w] = a1; }
    __syncthreads();
    if (t == 0) {
      float w0 = (sm[0] + sm[1] + sm[2] + sm[3]) * (1.0f / NN);
      float w1 = (sm[4] + sm[5] + sm[6] + sm[7]) * (1.0f / NN);
      float mx = fmaxf(w0, w1);
      float e0 = expf(w0 - mx), e1 = expf(w1 - mx);
      float inv = 1.f / (e0 + e1);
      wb[2] = e0 * inv;
      wb[3] = e1 * inv;
    }
  }
  int n = blockIdx.x * 4 + w;
  if (n >= NN) return;
  int r0 = rows[n], r1 = rows[n + 1];
  int eg = lane >> 4, fl = lane & 15;  // edge-in-group, feature lane (4 feats)
  float facc[4] = {0.f, 0.f, 0.f, 0.f};
  for (int j = r0; j < r1; j += 16) {  // clamped window: 4 loads always in flight
    int si[4];
    float sel[4];
#pragma unroll
    for (int t = 0; t < 4; ++t) {
      int jj = j + 4 * t + eg;
      int jx = jj < r1 ? jj : r1 - 1;
      si[t] = cols[jx];
      sel[t] = (jj < r1) ? 1.f : 0.f;
    }
    ushort4 xv[4];
#pragma unroll
    for (int t = 0; t < 4; ++t) xv[t] = *(const ushort4*)&X[(size_t)si[t] * 64 + fl * 4];
#pragma unroll
    for (int t = 0; t < 4; ++t) {
      facc[0] = fmaf(sel[t], bf2f(xv[t].x), facc[0]);
      facc[1] = fmaf(sel[t], bf2f(xv[t].y), facc[1]);
      facc[2] = fmaf(sel[t], bf2f(xv[t].z), facc[2]);
      facc[3] = fmaf(sel[t], bf2f(xv[t].w), facc[3]);
    }
  }
#pragma unroll
  for (int u = 0; u < 4; ++u) {
    facc[u] += __shfl_xor(facc[u], 16);
    facc[u] += __shfl_xor(facc[u], 32);
  }
  if (eg == 0) *(float4*)&psm[w][fl * 4] = make_float4(facc[0], facc[1], facc[2], facc[3]);
  __syncthreads();
  float p = tanhf(psm[w][lane] * rdi[n] + bg1[lane]);
  float o = 0.f;
#pragma unroll
  for (int k = 0; k < 64; ++k) o = fmaf(__shfl(p, k), Wg2[k * 64 + lane], o);
  out2[(size_t)n * 64 + lane] = f2bf(o * rdo[n]);
}

// ---------------- GCN gather layer2: clamped windows; inline Femb; Z + zero-padded Zk ------
__global__ __launch_bounds__(256) void gcn_gather2_kernel(
    const int* __restrict__ rows, const int* __restrict__ cols, const ushort_t* __restrict__ X,
    const float* __restrict__ rdi, const ushort_t* __restrict__ Y0,
    const ushort_t* __restrict__ Y1, const float* __restrict__ wb, const float* __restrict__ bf,
    const int* __restrict__ kptr, float* __restrict__ Zc, float* __restrict__ dout) {
  int lane = threadIdx.x & 63, w = threadIdx.x >> 6;
  int n = blockIdx.x * 4 + w;
  if (n >= NN) return;
  int r0 = rows[n], r1 = rows[n + 1];
  int eg = lane >> 4, fl = lane & 15;
  float facc[4] = {0.f, 0.f, 0.f, 0.f};
  for (int j = r0; j < r1; j += 16) {
    int si[4];
    float sel[4];
#pragma unroll
    for (int t = 0; t < 4; ++t) {
      int jj = j + 4 * t + eg;
      int jx = jj < r1 ? jj : r1 - 1;
      si[t] = cols[jx];
      sel[t] = (jj < r1) ? 1.f : 0.f;
    }
    ushort4 xv[4];
#pragma unroll
    for (int t = 0; t < 4; ++t) xv[t] = *(const ushort4*)&X[(size_t)si[t] * 64 + fl * 4];
#pragma unroll
    for (int t = 0; t < 4; ++t) {
      facc[0] = fmaf(sel[t], bf2f(xv[t].x), facc[0]);
      facc[1] = fmaf(sel[t], bf2f(xv[t].y), facc[1]);
      facc[2] = fmaf(sel[t], bf2f(xv[t].z), facc[2]);
      facc[3] = fmaf(sel[t], bf2f(xv[t].w), facc[3]);
    }
  }
#pragma unroll
  for (int u = 0; u < 4; ++u) {
    facc[u] += __shfl_xor(facc[u], 16);
    facc[u] += __shfl_xor(facc[u], 32);
  }
  if (eg == 0) {
    float ri = rdi[n];
    ushort4 y0 = *(const ushort4*)&Y0[(size_t)n * 64 + fl * 4];
    ushort4 y1 = *(const ushort4*)&Y1[(size_t)n * 64 + fl * 4];
    float4 bfv = *(const float4*)&bf[fl * 4];
    float w2 = wb[2], w3 = wb[3];
    float zv[4];
    zv[0] = 0.5f * (w2 * bf2f(y0.x) + w3 * bf2f(y1.x) + bfv.x + facc[0] * ri);
    zv[1] = 0.5f * (w2 * bf2f(y0.y) + w3 * bf2f(y1.y) + bfv.y + facc[1] * ri);
    zv[2] = 0.5f * (w2 * bf2f(y0.z) + w3 * bf2f(y1.z) + bfv.z + facc[2] * ri);
    zv[3] = 0.5f * (w2 * bf2f(y0.w) + w3 * bf2f(y1.w) + bfv.w + facc[3] * ri);
    float* dp = dout + 1 + (size_t)n * 64 + fl * 4;
    dp[0] = zv[0]; dp[1] = zv[1]; dp[2] = zv[2]; dp[3] = zv[3];
    int k = *kptr;
    if (fl < 4) {  // compact Zk, zero-padded to 16 for maskless tr
      float4 zk;
      zk.x = (fl * 4 + 0 < k) ? zv[0] : 0.f;
      zk.y = (fl * 4 + 1 < k) ? zv[1] : 0.f;
      zk.z = (fl * 4 + 2 < k) ? zv[2] : 0.f;
      zk.w = (fl * 4 + 3 < k) ? zv[3] : 0.f;
      *(float4*)&Zc[(size_t)n * 16 + fl * 4] = zk;
    }
  }
}

// ---------------- trace: 4 lanes/edge float4, 64 edges per block ----------------
__global__ __launch_bounds__(256) void tr_kernel(const int* __restrict__ asrc,
                                                 const int* __restrict__ adst,
                                                 const int* __restrict__ kptr,
                                                 const float* __restrict__ Zc,
                                                 const float* __restrict__ dout,
                                                 float* __restrict__ trbuf) {
  __shared__ float wsum[4];
  int lane = threadIdx.x & 63, w = threadIdx.x >> 6;
  int k = *kptr;
  int eg = lane >> 2, c0 = (lane & 3) * 4;
  int e = blockIdx.x * 64 + w * 16 + eg;
  float local = 0.f;
  if (e < NE) {
    int a = asrc[e], b = adst[e];
    if (k <= 16) {  // Zc zero-padded: no masking needed
      float4 za = *(const float4*)&Zc[(size_t)a * 16 + c0];
      float4 zb = *(const float4*)&Zc[(size_t)b * 16 + c0];
      float dx = za.x - zb.x, dy = za.y - zb.y, dz = za.z - zb.z, dw = za.w - zb.w;
      local = dx * dx + dy * dy + dz * dz + dw * dw;
    } else {
      const float* Za = dout + 1 + (size_t)a * 64;
      const float* Zb = dout + 1 + (size_t)b * 64;
#pragma unroll
      for (int st = 0; st < 4; ++st) {
#pragma unroll
        for (int t = 0; t < 4; ++t) {
          int c = c0 + st * 16 + t;
          if (c < k) {
            float d2 = Za[c] - Zb[c];
            local += d2 * d2;
          }
        }
      }
    }
  }
#pragma unroll
  for (int off = 32; off > 0; off >>= 1) local += __shfl_down(local, off);
  if (lane == 0) wsum[w] = local;
  __syncthreads();
  if (threadIdx.x == 0) trbuf[blockIdx.x] = wsum[0] + wsum[1] + wsum[2] + wsum[3];
}

__global__ __launch_bounds__(256) void tr_reduce_kernel(const float* __restrict__ trbuf,
                                                        float* __restrict__ dout) {
  __shared__ float sm[4];
  int t = threadIdx.x;
  float a = 0.f;
  for (int i = t; i < NTRB; i += 256) a += trbuf[i];
  a = wred(a);
  int lane = t & 63, w = t >> 6;
  if (lane == 0) sm[w] = a;
  __syncthreads();
  if (t == 0) dout[0] = 0.5f * (sm[0] + sm[1] + sm[2] + sm[3]);
}

extern "C" void kernel_launch(void* const* d_in, const int* in_sizes, int n_in, void* d_out,
                              int out_size, void* d_ws, size_t ws_size, hipStream_t stream) {
  const float* feat0 = (const float*)d_in[0];
  const float* feat1 = (const float*)d_in[1];
  const float* sen = (const float*)d_in[2];
  const float* Wgat0 = (const float*)d_in[3];
  const float* al0 = (const float*)d_in[4];
  const float* ar0 = (const float*)d_in[5];
  const float* b0 = (const float*)d_in[6];
  const float* Wgat1 = (const float*)d_in[7];
  const float* al1 = (const float*)d_in[8];
  const float* ar1 = (const float*)d_in[9];
  const float* b1 = (const float*)d_in[10];
  const float* Wp1 = (const float*)d_in[11];
  const float* bp1 = (const float*)d_in[12];
  const float* wp2 = (const float*)d_in[13];
  const float* Wf = (const float*)d_in[14];
  const float* bf = (const float*)d_in[15];
  const float* Wg1 = (const float*)d_in[16];
  const float* bg1 = (const float*)d_in[17];
  const float* Wg2 = (const float*)d_in[18];
  const int* src0 = (const int*)d_in[19];
  const int* dst0 = (const int*)d_in[20];
  const int* src1 = (const int*)d_in[21];
  const int* dst1 = (const int*)d_in[22];
  const int* gsrc = (const int*)d_in[23];
  const int* gdst = (const int*)d_in[24];
  const int* asrc = (const int*)d_in[25];
  const int* adst = (const int*)d_in[26];
  const int* kptr = (const int*)d_in[27];
  float* out = (float*)d_out;
  float* ws = (float*)d_ws;

  // ---- workspace layout (float-element offsets) ----
  float* wb = ws;                               // 4
  int* cnt = (int*)(ws + 4);                    // 4*30000
  int* cnt2 = (int*)(ws + 120004);              // 3*30000
  float* rdo = ws + 210004;                     // 30000
  float* rdi = ws + 240004;                     // 30000
  int* rows = (int*)(ws + 270004);              // 3*(NN+1)=90003
  int* bsum = (int*)(ws + 360008);              // 354
  int* boff = (int*)(ws + 360364);              // 354
  int* cols = (int*)(ws + 360720);              // 3*NE = 1,440,000
  float* el0 = ws + 1800720;                    // 120000
  float* er0 = ws + 1920720;                    // 120000
  float* el1 = ws + 2040720;                    // 120000
  float* er1 = ws + 2160720;                    // 120000
  float* pbuf = ws + 2280720;                   // 2*NMT = 470
  // trbuf (7500) reuses el0's region: el0 is dead after gat_node_kernel
  float* trbuf = el0;
  ushort_t* h0 = (ushort_t*)(ws + 2283068);     // 7,680,000 bf16
  ushort_t* h1 = (ushort_t*)(ws + 6123068);     // 7,680,000 bf16
  ushort_t* z0 = (ushort_t*)(ws + 9963068);     // 7,680,000 bf16 (fB0 before gat)
  ushort_t* z1 = (ushort_t*)(ws + 13803068);    // 7,680,000 bf16 (fB1 before gat)
  ushort_t* gcnA = (ushort_t*)(ws + 17643068);  // 1,920,000 bf16
  ushort_t* gcnA2 = (ushort_t*)(ws + 18603068); // 1,920,000 bf16
  ushort_t* Y0 = (ushort_t*)(ws + 19563068);    // 1,920,000 bf16
  ushort_t* Y1 = (ushort_t*)(ws + 20523068);    // 1,920,000 bf16
  ushort_t* WT0 = (ushort_t*)(ws + 21483068);   // 65536 bf16
  ushort_t* WT1 = (ushort_t*)(ws + 21515836);   // 32768 bf16
  ushort_t* WpfT = (ushort_t*)(ws + 21532220);  // 32768 bf16 = [Wp1T;WfT]
  ushort_t* Wg1T = (ushort_t*)(ws + 21548604);  // 16384 bf16
  float* Zc = ws + 21556796;                    // 480,000 (NN x 16 compact Zk)

  int* rows_g = rows + 2 * (NN + 1);
  int* cols_g = cols + 2 * NE;
  int* cnt_deg = cnt + 3 * NN;

  // fB0/fB1 alias z0/z1 (dead until gat_node overwrites them, after mfma_all)
  ushort_t* fB0 = z0;
  ushort_t* fB1 = z1;

  // ---- prep: zero + weight transposes + feat cvt (one launch; 1,639,957 items) ----
  prep_kernel<<<6407, 256, 0, stream>>>((float4*)ws, Wgat0, Wgat1, Wp1, Wf, Wg1, WT0, WT1, WpfT,
                                        WpfT + 16384, Wg1T, feat0, feat1, fB0, fB1);

  // ---- CSR build for 3 graphs (by dst) + gsrc out-degree ----
  hist_kernel<<<dim3(1875, 4), 256, 0, stream>>>(dst0, dst1, gdst, gsrc, cnt);
  scan_blocks_kernel<<<dim3(NBLK, 3), 256, 0, stream>>>(cnt, rows, bsum);
  scan_tops_kernel<<<dim3(1, 3), 128, 0, stream>>>(bsum, boff);
  add_off_kernel<<<dim3(NBLK, 3), 256, 0, stream>>>(rows, boff);
  scatter_kernel<<<dim3(1875, 4), 256, 0, stream>>>(src0, src1, gsrc, dst0, dst1, gdst, rows,
                                                    cnt2, cols, cnt_deg, rdo, rdi, rows_g);

  // ---- merged GEMM phase (LDS-free bf16 cores) ----
  mfma_all_kernel<<<dim3(NMT, 5), 256, 0, stream>>>(fB0, fB1, sen, WT0, WT1, Wg1T, h0, h1,
                                                    gcnA, al0, ar0, el0, er0, al1, ar1, el1,
                                                    er1, rdo);

  // ---- GAT gather (both graphs) -> bf16 z ----
  gat_node_kernel<<<dim3(7500, 2), 256, 0, stream>>>(rows, cols, el0, er0, h0, b0, z0,
                                                     rows + (NN + 1), cols + NE, el1, er1, h1,
                                                     b1, z1);

  // ---- merged attn pooling + Wf projection (LDS-free) ----
  mfma_attnwf_kernel<<<dim3(NMT, 2), 256, 0, stream>>>(z0, z1, WpfT, bp1, wp2, pbuf, Y0, Y1);

  // ---- GCN path ----
  gcn_gather12_kernel<<<7500, 256, 0, stream>>>(rows_g, cols_g, gcnA, rdi, bg1, Wg2, rdo, gcnA2,
                                                pbuf, wb);
  gcn_gather2_kernel<<<7500, 256, 0, stream>>>(rows_g, cols_g, gcnA2, rdi, Y0, Y1, wb, bf, kptr,
                                               Zc, out);

  // ---- trace ----
  tr_kernel<<<NTRB, 256, 0, stream>>>(asrc, adst, kptr, Zc, out, trbuf);
  tr_reduce_kernel<<<1, 256, 0, stream>>>(trbuf, out);
}

// Round 8
// 514.205 us; speedup vs baseline: 1.0330x; 1.0330x over previous
//
#include <hip/hip_runtime.h>
#include <math.h>

#define NN 30000
#define NE 480000
#define NBLK 118   // ceil(30000/256)
#define NMT 235    // ceil(30000/128) MFMA row-tiles
#define NTRB 7500  // blocks in tr pass (64 edges/block)
#define CAPD 128   // LDS-cached attention weights per node

typedef unsigned short ushort_t;
typedef unsigned int uint_t;
typedef __attribute__((ext_vector_type(8))) short short8;
typedef __attribute__((ext_vector_type(4))) float f32x4;

__device__ __forceinline__ ushort_t f2bf(float x) {
  uint_t u = __float_as_uint(x);
  u = (u + 0x7FFF + ((u >> 16) & 1)) >> 16;
  return (ushort_t)u;
}
__device__ __forceinline__ float bf2f(ushort_t v) {
  return __uint_as_float(((uint_t)v) << 16);
}

__device__ __forceinline__ float wred(float v) {
#pragma unroll
  for (int off = 32; off > 0; off >>= 1) v += __shfl_xor(v, off);
  return v;
}

// ---------------- prep: zero head + 5 weight transposes + feat0/feat1 -> bf16 ----------------
__global__ void prep_kernel(float4* __restrict__ zp, const float* __restrict__ W0,
                            const float* __restrict__ W1, const float* __restrict__ W2,
                            const float* __restrict__ W3, const float* __restrict__ W4,
                            ushort_t* __restrict__ T0, ushort_t* __restrict__ T1,
                            ushort_t* __restrict__ T2, ushort_t* __restrict__ T3,
                            ushort_t* __restrict__ T4, const float* __restrict__ F0,
                            const float* __restrict__ F1, ushort_t* __restrict__ B0,
                            ushort_t* __restrict__ B1) {
  int id = blockIdx.x * 256 + threadIdx.x;
  if (id < 52501) {
    zp[id] = make_float4(0.f, 0.f, 0.f, 0.f);
    return;
  }
  int wid = id - 52501;
  if (wid < 147456) {
    const float* W;
    ushort_t* T;
    int K, N, base;
    if (wid < 65536) { W = W0; T = T0; K = 256; N = 256; base = 0; }
    else if (wid < 98304) { W = W1; T = T1; K = 128; N = 256; base = 65536; }
    else if (wid < 114688) { W = W2; T = T2; K = 256; N = 64; base = 98304; }
    else if (wid < 131072) { W = W3; T = T3; K = 256; N = 64; base = 114688; }
    else { W = W4; T = T4; K = 256; N = 64; base = 131072; }
    int l = wid - base;
    int k = l / N, n = l - k * N;
    T[(size_t)n * K + k] = f2bf(W[l]);
    return;
  }
  int cid = wid - 147456;
  const float* S;
  ushort_t* D;
  if (cid < 960000) { S = F0; D = B0; }
  else {
    cid -= 960000;
    if (cid >= 480000) return;
    S = F1; D = B1;
  }
  const float4* p = (const float4*)(S + (size_t)cid * 8);
  float4 a = p[0], b = p[1];
  short8 o;
  o[0] = (short)f2bf(a.x); o[1] = (short)f2bf(a.y);
  o[2] = (short)f2bf(a.z); o[3] = (short)f2bf(a.w);
  o[4] = (short)f2bf(b.x); o[5] = (short)f2bf(b.y);
  o[6] = (short)f2bf(b.z); o[7] = (short)f2bf(b.w);
  *(short8*)(D + (size_t)cid * 8) = o;
}

// ================= MFMA cores =================

// BN=64 core, fp32 A (sen path)
__device__ __forceinline__ void mfma_core_f32(const float* __restrict__ A0,
                                              const ushort_t* __restrict__ BT, int K, int bm,
                                              short* __restrict__ As, short* __restrict__ Bs,
                                              f32x4 acc[2][4]) {
  int tid = threadIdx.x;
  int lane = tid & 63, w = tid >> 6;
  int q = lane >> 4, mr = lane & 15;
#pragma unroll 1
  for (int k0 = 0; k0 < K; k0 += 32) {
    {
      int r = tid >> 1, hf = tid & 1;
      int gr = bm + r;
      float4 f0 = make_float4(0.f, 0.f, 0.f, 0.f), f1 = f0, f2 = f0, f3 = f0;
      if (gr < NN) {
        const float4* pa = (const float4*)(A0 + (size_t)gr * K + k0 + hf * 16);
        f0 = pa[0]; f1 = pa[1]; f2 = pa[2]; f3 = pa[3];
      }
      short8 lo, hi;
      lo[0] = (short)f2bf(f0.x); lo[1] = (short)f2bf(f0.y);
      lo[2] = (short)f2bf(f0.z); lo[3] = (short)f2bf(f0.w);
      lo[4] = (short)f2bf(f1.x); lo[5] = (short)f2bf(f1.y);
      lo[6] = (short)f2bf(f1.z); lo[7] = (short)f2bf(f1.w);
      hi[0] = (short)f2bf(f2.x); hi[1] = (short)f2bf(f2.y);
      hi[2] = (short)f2bf(f2.z); hi[3] = (short)f2bf(f2.w);
      hi[4] = (short)f2bf(f3.x); hi[5] = (short)f2bf(f3.y);
      hi[6] = (short)f2bf(f3.z); hi[7] = (short)f2bf(f3.w);
      short* dst = As + r * 40 + hf * 16;
      *(short8*)(dst) = lo;
      *(short8*)(dst + 8) = hi;
    }
    {
      int n = tid >> 2, qk = tid & 3;
      short8 bv = *(const short8*)((const short*)BT + (size_t)n * K + k0 + qk * 8);
      *(short8*)(Bs + n * 40 + qk * 8) = bv;
    }
    __syncthreads();
    short8 a0 = *(short8*)(As + (w * 32 + mr) * 40 + q * 8);
    short8 a1 = *(short8*)(As + (w * 32 + 16 + mr) * 40 + q * 8);
#pragma unroll
    for (int j = 0; j < 4; ++j) {
      short8 b = *(short8*)(Bs + (j * 16 + mr) * 40 + q * 8);
      acc[0][j] = __builtin_amdgcn_mfma_f32_16x16x32_bf16(a0, b, acc[0][j], 0, 0, 0);
      acc[1][j] = __builtin_amdgcn_mfma_f32_16x16x32_bf16(a1, b, acc[1][j], 0, 0, 0);
    }
    __syncthreads();
  }
}

// BN=128 core, bf16 A, parametric K
__device__ __forceinline__ void mfma_core2_bfK(const ushort_t* __restrict__ A0,
                                               const ushort_t* __restrict__ BT, int K, int bm,
                                               short* __restrict__ As, short* __restrict__ Bs,
                                               f32x4 acc[2][8]) {
  int tid = threadIdx.x;
  int lane = tid & 63, w = tid >> 6;
  int q = lane >> 4, mr = lane & 15;
#pragma unroll 1
  for (int k0 = 0; k0 < K; k0 += 32) {
    {
      int r = tid >> 1, hf = tid & 1;
      int gr = bm + r;
      short8 v0 = {0, 0, 0, 0, 0, 0, 0, 0}, v1 = v0;
      if (gr < NN) {
        const short* p0 = (const short*)A0 + (size_t)gr * K + k0 + hf * 16;
        v0 = *(const short8*)p0;
        v1 = *(const short8*)(p0 + 8);
      }
      short* dst = As + r * 40 + hf * 16;
      *(short8*)(dst) = v0;
      *(short8*)(dst + 8) = v1;
    }
    {
      int n = tid >> 1, qk = tid & 1;
      const short* src = (const short*)BT + (size_t)n * K + k0 + qk * 16;
      short8 b0 = *(const short8*)src;
      short8 b1 = *(const short8*)(src + 8);
      short* d = Bs + n * 40 + qk * 16;
      *(short8*)d = b0;
      *(short8*)(d + 8) = b1;
    }
    __syncthreads();
    short8 a0 = *(short8*)(As + (w * 32 + mr) * 40 + q * 8);
    short8 a1 = *(short8*)(As + (w * 32 + 16 + mr) * 40 + q * 8);
#pragma unroll
    for (int j = 0; j < 8; ++j) {
      short8 b = *(short8*)(Bs + (j * 16 + mr) * 40 + q * 8);
      acc[0][j] = __builtin_amdgcn_mfma_f32_16x16x32_bf16(a0, b, acc[0][j], 0, 0, 0);
      acc[1][j] = __builtin_amdgcn_mfma_f32_16x16x32_bf16(a1, b, acc[1][j], 0, 0, 0);
    }
    __syncthreads();
  }
}

// ---- merged GEMM phase: grid (NMT, 5)
// y=0,1: h0 head-pairs (bf16 A); y=2,3: h1 head-pairs (bf16 A); y=4: gcn1 (fp32 sen)
__global__ __launch_bounds__(256) void mfma_all_kernel(
    const ushort_t* __restrict__ fB0, const ushort_t* __restrict__ fB1,
    const float* __restrict__ sen, const ushort_t* __restrict__ WT0,
    const ushort_t* __restrict__ WT1, const ushort_t* __restrict__ Wg1T,
    ushort_t* __restrict__ h0, ushort_t* __restrict__ h1, ushort_t* __restrict__ gcnA,
    const float* __restrict__ al0, const float* __restrict__ ar0, float* __restrict__ el0,
    float* __restrict__ er0, const float* __restrict__ al1, const float* __restrict__ ar1,
    float* __restrict__ el1, float* __restrict__ er1, const float* __restrict__ rdo) {
  __shared__ short As[128 * 40];
  __shared__ short Bs[128 * 40];
  int y = blockIdx.y;
  int bm = blockIdx.x * 128;
  int lane = threadIdx.x & 63, w = threadIdx.x >> 6;
  int q = lane >> 4, mr = lane & 15;
  if (y < 4) {
    int gsel = y >> 1, p = y & 1;
    const ushort_t* A = gsel ? fB1 : fB0;
    int K = gsel ? 128 : 256;
    const ushort_t* WT = gsel ? WT1 : WT0;
    ushort_t* H = gsel ? h1 : h0;
    const float* al = gsel ? al1 : al0;
    const float* ar = gsel ? ar1 : ar0;
    float* el = gsel ? el1 : el0;
    float* er = gsel ? er1 : er0;
    f32x4 acc[2][8];
#pragma unroll
    for (int i = 0; i < 2; ++i)
#pragma unroll
      for (int j = 0; j < 8; ++j) acc[i][j] = (f32x4){0.f, 0.f, 0.f, 0.f};
    mfma_core2_bfK(A, WT + (size_t)p * 128 * K, K, bm, As, Bs, acc);
    float alv[8], arv[8];
#pragma unroll
    for (int j = 0; j < 8; ++j) {
      alv[j] = al[p * 128 + j * 16 + mr];
      arv[j] = ar[p * 128 + j * 16 + mr];
    }
#pragma unroll
    for (int i = 0; i < 2; ++i)
#pragma unroll
      for (int r = 0; r < 4; ++r) {
        int gr = bm + w * 32 + i * 16 + q * 4 + r;
        float pl0 = 0.f, pr0 = 0.f, pl1 = 0.f, pr1 = 0.f;
#pragma unroll
        for (int j = 0; j < 4; ++j) {
          pl0 = fmaf(acc[i][j][r], alv[j], pl0);
          pr0 = fmaf(acc[i][j][r], arv[j], pr0);
          pl1 = fmaf(acc[i][j + 4][r], alv[j + 4], pl1);
          pr1 = fmaf(acc[i][j + 4][r], arv[j + 4], pr1);
        }
#pragma unroll
        for (int m = 1; m < 16; m <<= 1) {
          pl0 += __shfl_xor(pl0, m);
          pr0 += __shfl_xor(pr0, m);
          pl1 += __shfl_xor(pl1, m);
          pr1 += __shfl_xor(pr1, m);
        }
        if (gr < NN) {
          if (mr == 0) {
            el[gr * 4 + 2 * p] = pl0;
            er[gr * 4 + 2 * p] = pr0;
            el[gr * 4 + 2 * p + 1] = pl1;
            er[gr * 4 + 2 * p + 1] = pr1;
          }
#pragma unroll
          for (int j = 0; j < 8; ++j)
            H[(size_t)gr * 256 + p * 128 + j * 16 + mr] = f2bf(acc[i][j][r]);
        }
      }
  } else {
    f32x4 acc[2][4];
#pragma unroll
    for (int i = 0; i < 2; ++i)
#pragma unroll
      for (int j = 0; j < 4; ++j) acc[i][j] = (f32x4){0.f, 0.f, 0.f, 0.f};
    mfma_core_f32(sen, Wg1T, 256, bm, As, Bs, acc);
#pragma unroll
    for (int i = 0; i < 2; ++i)
#pragma unroll
      for (int r = 0; r < 4; ++r) {
        int gr = bm + w * 32 + i * 16 + q * 4 + r;
        if (gr < NN) {
          float sc = rdo[gr];
#pragma unroll
          for (int j = 0; j < 4; ++j)
            gcnA[(size_t)gr * 64 + j * 16 + mr] = f2bf(acc[i][j][r] * sc);
        }
      }
  }
}

// ---- attn + Wf projection merged (standalone; runs after gat) ----
__global__ __launch_bounds__(256) void mfma_attnwf_kernel(
    const ushort_t* __restrict__ z0, const ushort_t* __restrict__ z1,
    const ushort_t* __restrict__ WpfT, const float* __restrict__ bp1,
    const float* __restrict__ wp2, float* __restrict__ pbuf, ushort_t* __restrict__ Y0,
    ushort_t* __restrict__ Y1) {
  __shared__ short As[128 * 40];
  __shared__ short Bs[128 * 40];
  __shared__ float wsum[4];
  const ushort_t* A = blockIdx.y ? z1 : z0;
  ushort_t* Y = blockIdx.y ? Y1 : Y0;
  int bm = blockIdx.x * 128;
  f32x4 acc[2][8];
#pragma unroll
  for (int i = 0; i < 2; ++i)
#pragma unroll
    for (int j = 0; j < 8; ++j) acc[i][j] = (f32x4){0.f, 0.f, 0.f, 0.f};
  mfma_core2_bfK(A, WpfT, 256, bm, As, Bs, acc);
  int lane = threadIdx.x & 63, w = threadIdx.x >> 6;
  int q = lane >> 4, mr = lane & 15;
  float local = 0.f;
#pragma unroll
  for (int j = 0; j < 4; ++j) {
    int col = j * 16 + mr;
    float bp = bp1[col], wp = wp2[col];
#pragma unroll
    for (int i = 0; i < 2; ++i)
#pragma unroll
      for (int r = 0; r < 4; ++r) {
        int gr = bm + w * 32 + i * 16 + q * 4 + r;
        if (gr < NN) local += tanhf(acc[i][j][r] + bp) * wp;
      }
  }
  local = wred(local);
  if (lane == 0) wsum[w] = local;
#pragma unroll
  for (int j = 4; j < 8; ++j) {
    int col = (j - 4) * 16 + mr;
#pragma unroll
    for (int i = 0; i < 2; ++i)
#pragma unroll
      for (int r = 0; r < 4; ++r) {
        int gr = bm + w * 32 + i * 16 + q * 4 + r;
        if (gr < NN) Y[(size_t)gr * 64 + col] = f2bf(acc[i][j][r]);
      }
  }
  __syncthreads();
  if (threadIdx.x == 0)
    pbuf[blockIdx.y * NMT + blockIdx.x] = wsum[0] + wsum[1] + wsum[2] + wsum[3];
}

// ---------------- CSR build ----------------
__global__ void hist_kernel(const int* __restrict__ d0, const int* __restrict__ d1,
                            const int* __restrict__ d2, const int* __restrict__ d3,
                            int* __restrict__ cnt) {
  int g = blockIdx.y;
  const int* d = g == 0 ? d0 : g == 1 ? d1 : g == 2 ? d2 : d3;
  int e = blockIdx.x * 256 + threadIdx.x;
  if (e < NE) atomicAdd(&cnt[g * NN + d[e]], 1);
}

__global__ __launch_bounds__(256) void scan_blocks_kernel(const int* __restrict__ cnt,
                                                          int* __restrict__ rows,
                                                          int* __restrict__ bsum) {
  __shared__ int sm[256];
  int g = blockIdx.y, t = threadIdx.x;
  int i = blockIdx.x * 256 + t;
  int v = (i < NN) ? cnt[g * NN + i] : 0;
  sm[t] = v;
  __syncthreads();
#pragma unroll
  for (int off = 1; off < 256; off <<= 1) {
    int tmp = (t >= off) ? sm[t - off] : 0;
    __syncthreads();
    sm[t] += tmp;
    __syncthreads();
  }
  if (i < NN) rows[g * (NN + 1) + i] = sm[t] - v;  // exclusive
  if (t == 255) bsum[g * NBLK + blockIdx.x] = sm[255];
}

__global__ __launch_bounds__(128) void scan_tops_kernel(int* __restrict__ bsum,
                                                        int* __restrict__ boff) {
  __shared__ int sm[128];
  int g = blockIdx.y, t = threadIdx.x;
  int v = (t < NBLK) ? bsum[g * NBLK + t] : 0;
  sm[t] = v;
  __syncthreads();
#pragma unroll
  for (int off = 1; off < 128; off <<= 1) {
    int tmp = (t >= off) ? sm[t - off] : 0;
    __syncthreads();
    sm[t] += tmp;
    __syncthreads();
  }
  if (t < NBLK) boff[g * NBLK + t] = sm[t] - v;  // exclusive
}

__global__ void add_off_kernel(int* __restrict__ rows, const int* __restrict__ boff) {
  int g = blockIdx.y, t = threadIdx.x;
  int i = blockIdx.x * 256 + t;
  if (i < NN) rows[g * (NN + 1) + i] += boff[g * NBLK + blockIdx.x];
  if (blockIdx.x == 0 && t == 0) rows[g * (NN + 1) + NN] = NE;
}

// scatter (y=0..2) + rdeg (y=3)
__global__ void scatter_kernel(const int* __restrict__ s0, const int* __restrict__ s1,
                               const int* __restrict__ s2, const int* __restrict__ d0,
                               const int* __restrict__ d1, const int* __restrict__ d2,
                               const int* __restrict__ rows, int* __restrict__ cnt2,
                               int* __restrict__ cols, const int* __restrict__ cnt_deg,
                               float* __restrict__ rdo, float* __restrict__ rdi,
                               const int* __restrict__ rows_g) {
  int g = blockIdx.y;
  if (g == 3) {
    int n = blockIdx.x * 256 + threadIdx.x;
    if (n < NN) {
      rdo[n] = rsqrtf(fmaxf((float)cnt_deg[n], 1.f));
      float di = (float)(rows_g[n + 1] - rows_g[n]);
      rdi[n] = rsqrtf(fmaxf(di, 1.f));
    }
    return;
  }
  const int* sp = g == 0 ? s0 : g == 1 ? s1 : s2;
  const int* dp = g == 0 ? d0 : g == 1 ? d1 : d2;
  int e = blockIdx.x * 256 + threadIdx.x;
  if (e >= NE) return;
  int d = dp[e];
  int pos = rows[g * (NN + 1) + d] + atomicAdd(&cnt2[g * NN + d], 1);
  cols[(size_t)g * NE + pos] = sp[e];
}

// ---------------- GAT per-node gather: two-pass, aw in LDS, clamped 16-deep windows --------
__global__ __launch_bounds__(256) void gat_node_kernel(
    const int* __restrict__ rows0, const int* __restrict__ cols0, const float* __restrict__ el0,
    const float* __restrict__ er0, const ushort_t* __restrict__ h0,
    const float* __restrict__ bias0, ushort_t* __restrict__ zz0, const int* __restrict__ rows1,
    const int* __restrict__ cols1, const float* __restrict__ el1, const float* __restrict__ er1,
    const ushort_t* __restrict__ h1, const float* __restrict__ bias1,
    ushort_t* __restrict__ zz1) {
  __shared__ float aw[4][CAPD][4];  // 8 KB
  int g = blockIdx.y;
  const int* rows = g ? rows1 : rows0;
  const int* cols = g ? cols1 : cols0;
  const float* el = g ? el1 : el0;
  const float* er = g ? er1 : er0;
  const ushort_t* h = g ? h1 : h0;
  const float* bias = g ? bias1 : bias0;
  ushort_t* z = g ? zz1 : zz0;

  int lane = threadIdx.x & 63, w = threadIdx.x >> 6;
  int n = blockIdx.x * 4 + w;
  int r0 = rows[n], r1 = rows[n + 1];
  int deg = r1 - r0;
  float4 er4 = *(const float4*)&er[n * 4];
  float s0 = 0.f, s1 = 0.f, s2 = 0.f, s3 = 0.f;
  for (int j = lane; j < deg; j += 64) {
    int s = cols[r0 + j];
    float4 elv = *(const float4*)&el[s * 4];
    float v0 = elv.x + er4.x; v0 = v0 > 0.f ? v0 : 0.2f * v0;
    float v1 = elv.y + er4.y; v1 = v1 > 0.f ? v1 : 0.2f * v1;
    float v2 = elv.z + er4.z; v2 = v2 > 0.f ? v2 : 0.2f * v2;
    float v3 = elv.w + er4.w; v3 = v3 > 0.f ? v3 : 0.2f * v3;
    float e0 = __expf(v0), e1 = __expf(v1), e2 = __expf(v2), e3 = __expf(v3);
    s0 += e0; s1 += e1; s2 += e2; s3 += e3;
    if (j < CAPD) {
      aw[w][j][0] = e0; aw[w][j][1] = e1; aw[w][j][2] = e2; aw[w][j][3] = e3;
    }
  }
  s0 = wred(s0); s1 = wred(s1); s2 = wred(s2); s3 = wred(s3);
  __syncthreads();
  int hh = lane >> 4;
  float denom = hh == 0 ? s0 : hh == 1 ? s1 : hh == 2 ? s2 : s3;
  float myer = hh == 0 ? er4.x : hh == 1 ? er4.y : hh == 2 ? er4.z : er4.w;
  float invd = (deg > 0) ? 1.f / denom : 0.f;
  float4 acc = make_float4(0.f, 0.f, 0.f, 0.f);
  int jc = deg < CAPD ? deg : CAPD;
  // clamped 16-deep windows: 16 outstanding 512B row loads per wave, every iter
  for (int j = 0; j < jc; j += 16) {
    int si[16];
    float ai[16];
#pragma unroll
    for (int t = 0; t < 16; ++t) {
      int jj = j + t;
      int jx = jj < jc ? jj : jc - 1;
      si[t] = cols[r0 + jx];
      ai[t] = (jj < jc) ? aw[w][jj][hh] : 0.f;
    }
    ushort4 ui[16];
#pragma unroll
    for (int t = 0; t < 16; ++t) ui[t] = *(const ushort4*)&h[(size_t)si[t] * 256 + lane * 4];
#pragma unroll
    for (int t = 0; t < 16; ++t) {
      acc.x = fmaf(ai[t], bf2f(ui[t].x), acc.x);
      acc.y = fmaf(ai[t], bf2f(ui[t].y), acc.y);
      acc.z = fmaf(ai[t], bf2f(ui[t].z), acc.z);
      acc.w = fmaf(ai[t], bf2f(ui[t].w), acc.w);
    }
  }
  for (int j = jc; j < deg; ++j) {  // rare overflow beyond CAPD
    int s = cols[r0 + j];
    float v = el[s * 4 + hh] + myer;
    v = v > 0.f ? v : 0.2f * v;
    float a = __expf(v);
    ushort4 hu = *(const ushort4*)&h[(size_t)s * 256 + lane * 4];
    acc.x = fmaf(a, bf2f(hu.x), acc.x);
    acc.y = fmaf(a, bf2f(hu.y), acc.y);
    acc.z = fmaf(a, bf2f(hu.z), acc.z);
    acc.w = fmaf(a, bf2f(hu.w), acc.w);
  }
  float4 bv = *(const float4*)&bias[lane * 4];
  ushort4 o;
  o.x = f2bf(fminf(fmaxf(acc.x * invd + bv.x, 0.f), 6.f));
  o.y = f2bf(fminf(fmaxf(acc.y * invd + bv.y, 0.f), 6.f));
  o.z = f2bf(fminf(fmaxf(acc.z * invd + bv.z, 0.f), 6.f));
  o.w = f2bf(fminf(fmaxf(acc.w * invd + bv.w, 0.f), 6.f));
  *(ushort4*)&z[(size_t)n * 256 + lane * 4] = o;
}

// ---------------- GCN gather1 + gemm64 fused; clamped 16-edge windows; block 0 beta ----------
__global__ __launch_bounds__(256) void gcn_gather12_kernel(
    const int* __restrict__ rows, const int* __restrict__ cols, const ushort_t* __restrict__ X,
    const float* __restrict__ rdi, const float* __restrict__ bg1, const float* __restrict__ Wg2,
    const float* __restrict__ rdo, ushort_t* __restrict__ out2, const float* __restrict__ pbuf,
    float* __restrict__ wb) {
  __shared__ float psm[4][64];
  int lane = threadIdx.x & 63, w = threadIdx.x >> 6;
  // ---- folded attn_reduce (block 0 only) ----
  if (blockIdx.x == 0) {
    __shared__ float sm[8];
    int t = threadIdx.x;
    float a0 = 0.f, a1 = 0.f;
    for (int i = t; i < NMT; i += 256) {
      a0 += pbuf[i];
      a1 += pbuf[NMT + i];
    }
    a0 = wred(a0);
    a1 = wred(a1);
    if (lane == 0) { sm[w] = a0; sm[4 + w] = a1; }
    __syncthreads();
    if (t == 0) {
      float w0 = (sm[0] + sm[1] + sm[2] + sm[3]) * (1.0f / NN);
      float w1 = (sm[4] + sm[5] + sm[6] + sm[7]) * (1.0f / NN);
      float mx = fmaxf(w0, w1);
      float e0 = expf(w0 - mx), e1 = expf(w1 - mx);
      float inv = 1.f / (e0 + e1);
      wb[2] = e0 * inv;
      wb[3] = e1 * inv;
    }
  }
  int n = blockIdx.x * 4 + w;
  if (n >= NN) return;
  int r0 = rows[n], r1 = rows[n + 1];
  int eg = lane >> 4, fl = lane & 15;  // edge-in-group, feature lane (4 feats)
  float facc[4] = {0.f, 0.f, 0.f, 0.f};
  for (int j = r0; j < r1; j += 16) {  // clamped window: 4 loads always in flight
    int si[4];
    float sel[4];
#pragma unroll
    for (int t = 0; t < 4; ++t) {
      int jj = j + 4 * t + eg;
      int jx = jj < r1 ? jj : r1 - 1;
      si[t] = cols[jx];
      sel[t] = (jj < r1) ? 1.f : 0.f;
    }
    ushort4 xv[4];
#pragma unroll
    for (int t = 0; t < 4; ++t) xv[t] = *(const ushort4*)&X[(size_t)si[t] * 64 + fl * 4];
#pragma unroll
    for (int t = 0; t < 4; ++t) {
      facc[0] = fmaf(sel[t], bf2f(xv[t].x), facc[0]);
      facc[1] = fmaf(sel[t], bf2f(xv[t].y), facc[1]);
      facc[2] = fmaf(sel[t], bf2f(xv[t].z), facc[2]);
      facc[3] = fmaf(sel[t], bf2f(xv[t].w), facc[3]);
    }
  }
#pragma unroll
  for (int u = 0; u < 4; ++u) {
    facc[u] += __shfl_xor(facc[u], 16);
    facc[u] += __shfl_xor(facc[u], 32);
  }
  if (eg == 0) *(float4*)&psm[w][fl * 4] = make_float4(facc[0], facc[1], facc[2], facc[3]);
  __syncthreads();
  float p = tanhf(psm[w][lane] * rdi[n] + bg1[lane]);
  float o = 0.f;
#pragma unroll
  for (int k = 0; k < 64; ++k) o = fmaf(__shfl(p, k), Wg2[k * 64 + lane], o);
  out2[(size_t)n * 64 + lane] = f2bf(o * rdo[n]);
}

// ---------------- GCN gather layer2: clamped windows; inline Femb; Z + zero-padded Zk ------
__global__ __launch_bounds__(256) void gcn_gather2_kernel(
    const int* __restrict__ rows, const int* __restrict__ cols, const ushort_t* __restrict__ X,
    const float* __restrict__ rdi, const ushort_t* __restrict__ Y0,
    const ushort_t* __restrict__ Y1, const float* __restrict__ wb, const float* __restrict__ bf,
    const int* __restrict__ kptr, float* __restrict__ Zc, float* __restrict__ dout) {
  int lane = threadIdx.x & 63, w = threadIdx.x >> 6;
  int n = blockIdx.x * 4 + w;
  if (n >= NN) return;
  int r0 = rows[n], r1 = rows[n + 1];
  int eg = lane >> 4, fl = lane & 15;
  float facc[4] = {0.f, 0.f, 0.f, 0.f};
  for (int j = r0; j < r1; j += 16) {
    int si[4];
    float sel[4];
#pragma unroll
    for (int t = 0; t < 4; ++t) {
      int jj = j + 4 * t + eg;
      int jx = jj < r1 ? jj : r1 - 1;
      si[t] = cols[jx];
      sel[t] = (jj < r1) ? 1.f : 0.f;
    }
    ushort4 xv[4];
#pragma unroll
    for (int t = 0; t < 4; ++t) xv[t] = *(const ushort4*)&X[(size_t)si[t] * 64 + fl * 4];
#pragma unroll
    for (int t = 0; t < 4; ++t) {
      facc[0] = fmaf(sel[t], bf2f(xv[t].x), facc[0]);
      facc[1] = fmaf(sel[t], bf2f(xv[t].y), facc[1]);
      facc[2] = fmaf(sel[t], bf2f(xv[t].z), facc[2]);
      facc[3] = fmaf(sel[t], bf2f(xv[t].w), facc[3]);
    }
  }
#pragma unroll
  for (int u = 0; u < 4; ++u) {
    facc[u] += __shfl_xor(facc[u], 16);
    facc[u] += __shfl_xor(facc[u], 32);
  }
  if (eg == 0) {
    float ri = rdi[n];
    ushort4 y0 = *(const ushort4*)&Y0[(size_t)n * 64 + fl * 4];
    ushort4 y1 = *(const ushort4*)&Y1[(size_t)n * 64 + fl * 4];
    float4 bfv = *(const float4*)&bf[fl * 4];
    float w2 = wb[2], w3 = wb[3];
    float zv[4];
    zv[0] = 0.5f * (w2 * bf2f(y0.x) + w3 * bf2f(y1.x) + bfv.x + facc[0] * ri);
    zv[1] = 0.5f * (w2 * bf2f(y0.y) + w3 * bf2f(y1.y) + bfv.y + facc[1] * ri);
    zv[2] = 0.5f * (w2 * bf2f(y0.z) + w3 * bf2f(y1.z) + bfv.z + facc[2] * ri);
    zv[3] = 0.5f * (w2 * bf2f(y0.w) + w3 * bf2f(y1.w) + bfv.w + facc[3] * ri);
    float* dp = dout + 1 + (size_t)n * 64 + fl * 4;
    dp[0] = zv[0]; dp[1] = zv[1]; dp[2] = zv[2]; dp[3] = zv[3];
    int k = *kptr;
    if (fl < 4) {  // compact Zk, zero-padded to 16 for maskless tr
      float4 zk;
      zk.x = (fl * 4 + 0 < k) ? zv[0] : 0.f;
      zk.y = (fl * 4 + 1 < k) ? zv[1] : 0.f;
      zk.z = (fl * 4 + 2 < k) ? zv[2] : 0.f;
      zk.w = (fl * 4 + 3 < k) ? zv[3] : 0.f;
      *(float4*)&Zc[(size_t)n * 16 + fl * 4] = zk;
    }
  }
}

// ---------------- trace: 4 lanes/edge float4, 64 edges per block ----------------
__global__ __launch_bounds__(256) void tr_kernel(const int* __restrict__ asrc,
                                                 const int* __restrict__ adst,
                                                 const int* __restrict__ kptr,
                                                 const float* __restrict__ Zc,
                                                 const float* __restrict__ dout,
                                                 float* __restrict__ trbuf) {
  __shared__ float wsum[4];
  int lane = threadIdx.x & 63, w = threadIdx.x >> 6;
  int k = *kptr;
  int eg = lane >> 2, c0 = (lane & 3) * 4;
  int e = blockIdx.x * 64 + w * 16 + eg;
  float local = 0.f;
  if (e < NE) {
    int a = asrc[e], b = adst[e];
    if (k <= 16) {  // Zc zero-padded: no masking needed
      float4 za = *(const float4*)&Zc[(size_t)a * 16 + c0];
      float4 zb = *(const float4*)&Zc[(size_t)b * 16 + c0];
      float dx = za.x - zb.x, dy = za.y - zb.y, dz = za.z - zb.z, dw = za.w - zb.w;
      local = dx * dx + dy * dy + dz * dz + dw * dw;
    } else {
      const float* Za = dout + 1 + (size_t)a * 64;
      const float* Zb = dout + 1 + (size_t)b * 64;
#pragma unroll
      for (int st = 0; st < 4; ++st) {
#pragma unroll
        for (int t = 0; t < 4; ++t) {
          int c = c0 + st * 16 + t;
          if (c < k) {
            float d2 = Za[c] - Zb[c];
            local += d2 * d2;
          }
        }
      }
    }
  }
#pragma unroll
  for (int off = 32; off > 0; off >>= 1) local += __shfl_down(local, off);
  if (lane == 0) wsum[w] = local;
  __syncthreads();
  if (threadIdx.x == 0) trbuf[blockIdx.x] = wsum[0] + wsum[1] + wsum[2] + wsum[3];
}

__global__ __launch_bounds__(256) void tr_reduce_kernel(const float* __restrict__ trbuf,
                                                        float* __restrict__ dout) {
  __shared__ float sm[4];
  int t = threadIdx.x;
  float a = 0.f;
  for (int i = t; i < NTRB; i += 256) a += trbuf[i];
  a = wred(a);
  int lane = t & 63, w = t >> 6;
  if (lane == 0) sm[w] = a;
  __syncthreads();
  if (t == 0) dout[0] = 0.5f * (sm[0] + sm[1] + sm[2] + sm[3]);
}

extern "C" void kernel_launch(void* const* d_in, const int* in_sizes, int n_in, void* d_out,
                              int out_size, void* d_ws, size_t ws_size, hipStream_t stream) {
  const float* feat0 = (const float*)d_in[0];
  const float* feat1 = (const float*)d_in[1];
  const float* sen = (const float*)d_in[2];
  const float* Wgat0 = (const float*)d_in[3];
  const float* al0 = (const float*)d_in[4];
  const float* ar0 = (const float*)d_in[5];
  const float* b0 = (const float*)d_in[6];
  const float* Wgat1 = (const float*)d_in[7];
  const float* al1 = (const float*)d_in[8];
  const float* ar1 = (const float*)d_in[9];
  const float* b1 = (const float*)d_in[10];
  const float* Wp1 = (const float*)d_in[11];
  const float* bp1 = (const float*)d_in[12];
  const float* wp2 = (const float*)d_in[13];
  const float* Wf = (const float*)d_in[14];
  const float* bf = (const float*)d_in[15];
  const float* Wg1 = (const float*)d_in[16];
  const float* bg1 = (const float*)d_in[17];
  const float* Wg2 = (const float*)d_in[18];
  const int* src0 = (const int*)d_in[19];
  const int* dst0 = (const int*)d_in[20];
  const int* src1 = (const int*)d_in[21];
  const int* dst1 = (const int*)d_in[22];
  const int* gsrc = (const int*)d_in[23];
  const int* gdst = (const int*)d_in[24];
  const int* asrc = (const int*)d_in[25];
  const int* adst = (const int*)d_in[26];
  const int* kptr = (const int*)d_in[27];
  float* out = (float*)d_out;
  float* ws = (float*)d_ws;

  // ---- workspace layout (float-element offsets) ----
  float* wb = ws;                               // 4
  int* cnt = (int*)(ws + 4);                    // 4*30000
  int* cnt2 = (int*)(ws + 120004);              // 3*30000
  float* rdo = ws + 210004;                     // 30000
  float* rdi = ws + 240004;                     // 30000
  int* rows = (int*)(ws + 270004);              // 3*(NN+1)=90003
  int* bsum = (int*)(ws + 360008);              // 354
  int* boff = (int*)(ws + 360364);              // 354
  int* cols = (int*)(ws + 360720);              // 3*NE = 1,440,000
  float* el0 = ws + 1800720;                    // 120000
  float* er0 = ws + 1920720;                    // 120000
  float* el1 = ws + 2040720;                    // 120000
  float* er1 = ws + 2160720;                    // 120000
  float* pbuf = ws + 2280720;                   // 2*NMT = 470
  // trbuf (7500) reuses el0's region: el0 is dead after gat_node_kernel
  float* trbuf = el0;
  ushort_t* h0 = (ushort_t*)(ws + 2283068);     // 7,680,000 bf16
  ushort_t* h1 = (ushort_t*)(ws + 6123068);     // 7,680,000 bf16
  ushort_t* z0 = (ushort_t*)(ws + 9963068);     // 7,680,000 bf16 (fB0 before gat)
  ushort_t* z1 = (ushort_t*)(ws + 13803068);    // 7,680,000 bf16 (fB1 before gat)
  ushort_t* gcnA = (ushort_t*)(ws + 17643068);  // 1,920,000 bf16
  ushort_t* gcnA2 = (ushort_t*)(ws + 18603068); // 1,920,000 bf16
  ushort_t* Y0 = (ushort_t*)(ws + 19563068);    // 1,920,000 bf16
  ushort_t* Y1 = (ushort_t*)(ws + 20523068);    // 1,920,000 bf16
  ushort_t* WT0 = (ushort_t*)(ws + 21483068);   // 65536 bf16
  ushort_t* WT1 = (ushort_t*)(ws + 21515836);   // 32768 bf16
  ushort_t* WpfT = (ushort_t*)(ws + 21532220);  // 32768 bf16 = [Wp1T;WfT]
  ushort_t* Wg1T = (ushort_t*)(ws + 21548604);  // 16384 bf16
  float* Zc = ws + 21556796;                    // 480,000 (NN x 16 compact Zk)

  int* rows_g = rows + 2 * (NN + 1);
  int* cols_g = cols + 2 * NE;
  int* cnt_deg = cnt + 3 * NN;

  // fB0/fB1 alias z0/z1 (dead until gat_node overwrites them, after mfma_all)
  ushort_t* fB0 = z0;
  ushort_t* fB1 = z1;

  // ---- prep: zero + weight transposes + feat cvt (one launch; 1,639,957 items) ----
  prep_kernel<<<6407, 256, 0, stream>>>((float4*)ws, Wgat0, Wgat1, Wp1, Wf, Wg1, WT0, WT1, WpfT,
                                        WpfT + 16384, Wg1T, feat0, feat1, fB0, fB1);

  // ---- CSR build for 3 graphs (by dst) + gsrc out-degree ----
  hist_kernel<<<dim3(1875, 4), 256, 0, stream>>>(dst0, dst1, gdst, gsrc, cnt);
  scan_blocks_kernel<<<dim3(NBLK, 3), 256, 0, stream>>>(cnt, rows, bsum);
  scan_tops_kernel<<<dim3(1, 3), 128, 0, stream>>>(bsum, boff);
  add_off_kernel<<<dim3(NBLK, 3), 256, 0, stream>>>(rows, boff);
  scatter_kernel<<<dim3(1875, 4), 256, 0, stream>>>(src0, src1, gsrc, dst0, dst1, gdst, rows,
                                                    cnt2, cols, cnt_deg, rdo, rdi, rows_g);

  // ---- merged GEMM phase ----
  mfma_all_kernel<<<dim3(NMT, 5), 256, 0, stream>>>(fB0, fB1, sen, WT0, WT1, Wg1T, h0, h1,
                                                    gcnA, al0, ar0, el0, er0, al1, ar1, el1,
                                                    er1, rdo);

  // ---- GAT gather (both graphs) -> bf16 z ----
  gat_node_kernel<<<dim3(7500, 2), 256, 0, stream>>>(rows, cols, el0, er0, h0, b0, z0,
                                                     rows + (NN + 1), cols + NE, el1, er1, h1,
                                                     b1, z1);

  // ---- merged attn pooling + Wf projection ----
  mfma_attnwf_kernel<<<dim3(NMT, 2), 256, 0, stream>>>(z0, z1, WpfT, bp1, wp2, pbuf, Y0, Y1);

  // ---- GCN path ----
  gcn_gather12_kernel<<<7500, 256, 0, stream>>>(rows_g, cols_g, gcnA, rdi, bg1, Wg2, rdo, gcnA2,
                                                pbuf, wb);
  gcn_gather2_kernel<<<7500, 256, 0, stream>>>(rows_g, cols_g, gcnA2, rdi, Y0, Y1, wb, bf, kptr,
                                               Zc, out);

  // ---- trace ----
  tr_kernel<<<NTRB, 256, 0, stream>>>(asrc, adst, kptr, Zc, out, trbuf);
  tr_reduce_kernel<<<1, 256, 0, stream>>>(trbuf, out);
}